// Round 5
// baseline (17040.375 us; speedup 1.0000x reference)
//
#include <hip/hip_runtime.h>
#include <cstdint>
#include <cstddef>

#define Bz 64
#define Tz 512
#define Iz 512
#define Hz 512
#define Cz 4096
#define NWG 256

typedef __attribute__((ext_vector_type(8))) short short8;
typedef __attribute__((ext_vector_type(4))) float floatx4;
typedef __attribute__((ext_vector_type(2))) float floatx2;
typedef unsigned long long u64;
typedef unsigned int u32;

union U16S8 { u64 u[2]; short8 s; };
union U8F2  { u64 u; float f[2]; };

__device__ __forceinline__ unsigned short f2bf(float f) {
  union { float f; unsigned u; } v; v.f = f;
  unsigned r = v.u + 0x7fffu + ((v.u >> 16) & 1u);
  return (unsigned short)(r >> 16);
}
__device__ __forceinline__ float bf2f(unsigned short h) {
  union { unsigned u; float f; } v; v.u = ((unsigned)h) << 16; return v.f;
}
__device__ __forceinline__ float sigmoidf_(float x) { return 1.0f / (1.0f + __expf(-x)); }

// coherent 16-B read = two relaxed agent-scope u64 loads (lower to sc1 loads: bypass
// stale L1/L2, read the coherence point; no invalidate, no atomic RMW unit).
__device__ __forceinline__ short8 ald16(const void* p) {
  u64* q = (u64*)p;
  U16S8 t;
  t.u[0] = __hip_atomic_load(q,     __ATOMIC_RELAXED, __HIP_MEMORY_SCOPE_AGENT);
  t.u[1] = __hip_atomic_load(q + 1, __ATOMIC_RELAXED, __HIP_MEMORY_SCOPE_AGENT);
  return t.s;
}

// ---------------- precast kernels (packed path) ----------------

__global__ __launch_bounds__(256) void precast_wpk(const float* __restrict__ Wi,
                                                   const float* __restrict__ Wst,
                                                   short* __restrict__ wpk) {
  int id = blockIdx.x * 256 + threadIdx.x;       // 0..2097151
  int l  = id & 63;
  int kt = (id >> 6) & 31;
  int nt = (id >> 11) & 3;
  int w  = id >> 13;
  int r  = nt * Cz + w * 16 + (l & 15);
  int k  = kt * 32 + (l >> 4) * 8;
  const float* p = (k < Iz) ? (Wi + (size_t)r * Iz + k)
                            : (Wst + (size_t)r * Hz + (k - Iz));
  short8 v;
  #pragma unroll
  for (int i = 0; i < 8; ++i) v[i] = (short)f2bf(p[i]);
  *(short8*)(wpk + (size_t)id * 8) = v;
}

__global__ __launch_bounds__(256) void precast_wpp(const float* __restrict__ Wp,
                                                   short* __restrict__ wpp) {
  int id = blockIdx.x * 256 + threadIdx.x;       // 0..262143
  int l  = id & 63;
  int kt = (id >> 6) & 15;
  int jc = (id >> 10) & 31;
  int kc = id >> 15;
  int j  = jc * 16 + (l & 15);
  int c  = kc * 512 + kt * 32 + (l >> 4) * 8;
  const float* p = Wp + (size_t)j * Cz + c;
  short8 v;
  #pragma unroll
  for (int i = 0; i < 8; ++i) v[i] = (short)f2bf(p[i]);
  *(short8*)(wpp + (size_t)id * 8) = v;
}

__global__ __launch_bounds__(256) void precast_x(const float* __restrict__ x,
                                                 unsigned short* __restrict__ xb) {
  size_t id = ((size_t)blockIdx.x * 256 + threadIdx.x) * 4;
  float4 v = *(const float4*)(x + id);
  ushort4 o;
  o.x = f2bf(v.x); o.y = f2bf(v.y); o.z = f2bf(v.z); o.w = f2bf(v.w);
  *(ushort4*)(xb + id) = o;
}

// ---------------- persistent kernel: 256 WGs x 512 thr ----------------
// WG w: gates for cells [w*16, w*16+16); proj tile kc=w>>5, jc=w&31.
// WGs with kc==7 are the designated finalizers for their jc.
// Coherence: only relaxed sc1 loads/stores + barriers. No RMW atomics, no fences.
template <bool PK>
__global__ __launch_bounds__(512, 2)
void lstm_persist(const float* __restrict__ xf, const unsigned short* __restrict__ xb,
                  const float* __restrict__ Wi, const float* __restrict__ Wst,
                  const float* __restrict__ Wp,
                  const short* __restrict__ wpk, const short* __restrict__ wpp,
                  const float* __restrict__ bstate, const int* __restrict__ lens,
                  unsigned short* __restrict__ Hrep,   // 2 parity x 8 rep x [64][512] bf16
                  float* __restrict__ part,            // 8 x [64][512] fp32
                  int* __restrict__ afl,               // 4 rep x 256 flags (stride 16 ints)
                  int* __restrict__ hfl,               // 8 rep x 32 flags
                  int* __restrict__ pfl,               // 256 flags
                  unsigned short* __restrict__ abuf,   // 2 parity x 4 rep x [64][4096] bf16
                  float* __restrict__ outp, float* __restrict__ final_h,
                  float* __restrict__ final_c) {
  __shared__ __align__(16) short astage[2][64 * 16 * 8];  // 2 x 16 KB
  __shared__ float glds[64 * 64];                         // 16 KB, XOR-swizzled cols

  const int tid  = threadIdx.x;
  const int w    = blockIdx.x;
  const int lane = tid & 63;
  const int wv   = tid >> 6;        // 0..7
  const int lrow = lane & 15;
  const int lq   = lane >> 4;
  const int bt   = wv >> 1;         // gates batch 16-tile
  const int ntb  = (wv & 1) * 2;    // gates gate-pair base {0,2}
  const int jc   = w & 31;
  const int kc   = w >> 5;
  const bool isFinal = (kc == 7);

  // epilogue ownership: thread -> (batch b_e, cells cc2, cc2+1)
  const int b_e  = tid >> 3;        // 0..63
  const int cc2  = (tid & 7) * 2;   // 0..14
  const int cell2 = w * 16 + cc2;
  float bsv[4][2];
  #pragma unroll
  for (int g = 0; g < 4; ++g) {
    bsv[g][0] = bstate[g * Cz + cell2];
    bsv[g][1] = bstate[g * Cz + cell2 + 1];
  }
  const int len_e = lens[b_e];
  float c_reg[2] = {0.f, 0.f};

  // finalizer ownership: thread -> (batch b_f, cols jf, jf+1)
  const int b_f = tid >> 3;
  const int jf  = jc * 16 + (tid & 7) * 2;
  const int len_f = lens[b_f];

  for (int t = 0; t < Tz; ++t) {
    const unsigned short* HrepR = Hrep + ((size_t)(t & 1) * 8 + (w & 7)) * Bz * Hz;

    // =================== gates phase ===================
    floatx4 acc0 = {0.f, 0.f, 0.f, 0.f};
    floatx4 acc1 = {0.f, 0.f, 0.f, 0.f};

    auto gmfma = [&](const short* sb, int ktbase) {
      #pragma unroll
      for (int ktl = 0; ktl < 4; ++ktl) {
        const int kt = ktbase + ktl;
        int grp  = ktl * 4 + lq;
        int phys = grp ^ lrow;
        short8 afr = *(const short8*)(sb + ((bt * 16 + lrow) * 16 + phys) * 8);
        short8 bfr0, bfr1;
        if (PK) {
          const short* bp = wpk + ((((size_t)w * 4 + ntb) * 32 + kt) * 64 + lane) * 8;
          bfr0 = *(const short8*)bp;
          bfr1 = *(const short8*)(bp + (size_t)32 * 64 * 8);
        } else {
          #pragma unroll
          for (int hh = 0; hh < 2; ++hh) {
            int nt = ntb + hh;
            int r  = nt * Cz + w * 16 + lrow;
            int k  = kt * 32 + lq * 8;
            const float* p = (k < Iz) ? (Wi + (size_t)r * Iz + k)
                                      : (Wst + (size_t)r * Hz + (k - Iz));
            short8 v;
            #pragma unroll
            for (int i = 0; i < 8; ++i) v[i] = (short)f2bf(p[i]);
            if (hh == 0) bfr0 = v; else bfr1 = v;
          }
        }
        acc0 = __builtin_amdgcn_mfma_f32_16x16x32_bf16(afr, bfr0, acc0, 0, 0, 0);
        acc1 = __builtin_amdgcn_mfma_f32_16x16x32_bf16(afr, bfr1, acc1, 0, 0, 0);
      }
    };

    // ---- x half: chunks 0..3, no h dependency, L2-cached reads ----
    auto stage_x = [&](int q, int buf) {
      const int k0 = q * 128;
      #pragma unroll
      for (int u = 0; u < 2; ++u) {
        int idx = u * 512 + tid;
        int row = idx >> 4;
        int grp = idx & 15;
        int k = k0 + grp * 8;
        short8 val;
        if (PK) {
          val = *(const short8*)(xb + ((size_t)row * Tz + t) * Iz + k);
        } else {
          const float* p = xf + ((size_t)row * Tz + t) * Iz + k;
          #pragma unroll
          for (int i = 0; i < 8; ++i) val[i] = (short)f2bf(p[i]);
        }
        int phys = grp ^ (row & 15);
        *(short8*)(&astage[buf][(row * 16 + phys) * 8]) = val;
      }
    };

    stage_x(0, 0);
    __syncthreads();
    for (int q = 0; q < 4; ++q) {
      if (q < 3) stage_x(q + 1, (q + 1) & 1);
      gmfma(astage[q & 1], q * 4);
      __syncthreads();
    }

    // ---- wait: h(t-1) complete (poll this WG's hflag replica set) ----
    if (tid < 32) {
      while (__hip_atomic_load(&hfl[((w & 7) * 32 + tid) * 16], __ATOMIC_RELAXED,
                               __HIP_MEMORY_SCOPE_AGENT) < t)
        __builtin_amdgcn_s_sleep(1);
    }
    __syncthreads();
    __asm__ volatile("" ::: "memory");

    // ---- h half: prefetch all 4 chunks to regs (sc1), then stage+MFMA ----
    short8 hpf[4][2];
    #pragma unroll
    for (int qq = 0; qq < 4; ++qq) {
      #pragma unroll
      for (int u = 0; u < 2; ++u) {
        int idx = u * 512 + tid;
        int row = idx >> 4;
        int grp = idx & 15;
        hpf[qq][u] = ald16(HrepR + row * Hz + qq * 128 + grp * 8);
      }
    }
    #pragma unroll
    for (int qq = 0; qq < 4; ++qq) {
      #pragma unroll
      for (int u = 0; u < 2; ++u) {
        int idx = u * 512 + tid;
        int row = idx >> 4;
        int grp = idx & 15;
        int phys = grp ^ (row & 15);
        *(short8*)(&astage[qq & 1][(row * 16 + phys) * 8]) = hpf[qq][u];
      }
      __syncthreads();
      gmfma(astage[qq & 1], 16 + qq * 4);
      __syncthreads();
    }

    {  // spill gate tile to LDS; col n = gate*16 + cell, phys col = n ^ row
      const int sb0 = bt * 16 + lq * 4;
      const int n0  = ntb * 16 + lrow;
      #pragma unroll
      for (int r = 0; r < 4; ++r) {
        int row = sb0 + r;
        glds[row * 64 + ((n0 ^ row) & 63)]        = acc0[r];
        glds[row * 64 + (((n0 + 16) ^ row) & 63)] = acc1[r];
      }
    }
    __syncthreads();
    {  // fp32 epilogue: 2 cells/thread, c in regs, 4 abuf replica stores (sc1)
      float a_out[2];
      #pragma unroll
      for (int e = 0; e < 2; ++e) {
        int cc = cc2 + e;
        float g0 = glds[b_e * 64 + (((0  + cc) ^ b_e) & 63)] + bsv[0][e];
        float g1 = glds[b_e * 64 + (((16 + cc) ^ b_e) & 63)] + bsv[1][e];
        float g2 = glds[b_e * 64 + (((32 + cc) ^ b_e) & 63)] + bsv[2][e];
        float g3 = glds[b_e * 64 + (((48 + cc) ^ b_e) & 63)] + bsv[3][e];
        float mem = sigmoidf_(g0) * tanhf(g2) + sigmoidf_(g1) * c_reg[e];
        mem = fminf(fmaxf(mem, -3.f), 3.f);
        bool active = t < len_e;
        c_reg[e] = active ? mem : c_reg[e];
        a_out[e] = sigmoidf_(g3) * tanhf(mem);
      }
      u32 pk2 = (u32)f2bf(a_out[0]) | ((u32)f2bf(a_out[1]) << 16);
      u32* ab32 = (u32*)(abuf + (size_t)(t & 1) * 4 * Bz * Cz);
      size_t aidx = ((size_t)b_e * Cz + cell2) >> 1;
      #pragma unroll
      for (int rep = 0; rep < 4; ++rep)
        __hip_atomic_store(ab32 + (size_t)rep * (Bz * Cz / 2) + aidx, pk2,
                           __ATOMIC_RELAXED, __HIP_MEMORY_SCOPE_AGENT);
      if (t == Tz - 1) {
        __builtin_nontemporal_store(c_reg[0], final_c + (size_t)b_e * Cz + cell2);
        __builtin_nontemporal_store(c_reg[1], final_c + (size_t)b_e * Cz + cell2 + 1);
      }
    }
    __syncthreads();            // every wave drained vmcnt(0) -> abuf at IC
    if (tid == 0) {             // publish aflag replicas (relaxed: sc1 stores ordered by drain)
      __asm__ volatile("s_waitcnt vmcnt(0)" ::: "memory");
      #pragma unroll
      for (int rep = 0; rep < 4; ++rep)
        __hip_atomic_store(&afl[(rep * 256 + w) * 16], t + 1,
                           __ATOMIC_RELAXED, __HIP_MEMORY_SCOPE_AGENT);
    }

    // ---- wait: 32 producers of abuf columns [kc*512, kc*512+512) ----
    if (tid < 32) {
      while (__hip_atomic_load(&afl[((jc & 3) * 256 + kc * 32 + tid) * 16],
                               __ATOMIC_RELAXED, __HIP_MEMORY_SCOPE_AGENT) < t + 1)
        __builtin_amdgcn_s_sleep(1);
    }
    __syncthreads();
    __asm__ volatile("" ::: "memory");

    // =================== projection phase ===================
    const unsigned short* abufR = abuf + ((size_t)(t & 1) * 4 + (jc & 3)) * Bz * Cz;
    floatx4 pacc = {0.f, 0.f, 0.f, 0.f};

    short8 ppf[4][2];
    #pragma unroll
    for (int ch = 0; ch < 4; ++ch) {
      #pragma unroll
      for (int u = 0; u < 2; ++u) {
        int idx = u * 512 + tid;
        int row = idx >> 4;
        int grp = idx & 15;
        ppf[ch][u] = ald16(abufR + (size_t)row * Cz + kc * 512 + ch * 128 + grp * 8);
      }
    }
    #pragma unroll
    for (int ch = 0; ch < 4; ++ch) {
      #pragma unroll
      for (int u = 0; u < 2; ++u) {
        int idx = u * 512 + tid;
        int row = idx >> 4;
        int grp = idx & 15;
        int phys = grp ^ (row & 15);
        *(short8*)(&astage[ch & 1][(row * 16 + phys) * 8]) = ppf[ch][u];
      }
      __syncthreads();
      if (wv < 4) {
        const short* sb = astage[ch & 1];
        #pragma unroll
        for (int ktl = 0; ktl < 4; ++ktl) {
          int kt   = ch * 4 + ktl;
          int grp  = ktl * 4 + lq;
          int phys = grp ^ lrow;
          short8 afr = *(const short8*)(sb + ((wv * 16 + lrow) * 16 + phys) * 8);
          short8 bfr;
          if (PK) {
            bfr = *(const short8*)(wpp + ((((size_t)kc * 32 + jc) * 16 + kt) * 64 + lane) * 8);
          } else {
            int j = jc * 16 + lrow;
            int c = kc * 512 + kt * 32 + lq * 8;
            const float* p = Wp + (size_t)j * Cz + c;
            #pragma unroll
            for (int i = 0; i < 8; ++i) bfr[i] = (short)f2bf(p[i]);
          }
          pacc = __builtin_amdgcn_mfma_f32_16x16x32_bf16(afr, bfr, pacc, 0, 0, 0);
        }
      }
      __syncthreads();
    }
    if (wv < 4) {  // plain relaxed sc1 stores of partials (no RMW)
      const int jcol = jc * 16 + lrow;
      #pragma unroll
      for (int r = 0; r < 4; ++r)
        __hip_atomic_store(part + (size_t)kc * Bz * Hz + (wv * 16 + lq * 4 + r) * Hz + jcol,
                           pacc[r], __ATOMIC_RELAXED, __HIP_MEMORY_SCOPE_AGENT);
    }
    __syncthreads();            // drain partial stores
    if (tid == 0) {
      __asm__ volatile("s_waitcnt vmcnt(0)" ::: "memory");
      __hip_atomic_store(&pfl[(kc * 32 + jc) * 16], t + 1,
                         __ATOMIC_RELAXED, __HIP_MEMORY_SCOPE_AGENT);
    }

    // =================== finalize (fixed kc==7 WG per jc) ===================
    if (isFinal) {
      if (tid < 7) {
        while (__hip_atomic_load(&pfl[(tid * 32 + jc) * 16], __ATOMIC_RELAXED,
                                 __HIP_MEMORY_SCOPE_AGENT) < t + 1)
          __builtin_amdgcn_s_sleep(1);
      }
      __syncthreads();
      __asm__ volatile("" ::: "memory");

      float v0 = 0.f, v1 = 0.f;
      #pragma unroll
      for (int k8 = 0; k8 < 8; ++k8) {
        U8F2 pa;
        pa.u = __hip_atomic_load((u64*)(part + (size_t)k8 * Bz * Hz + b_f * Hz + jf),
                                 __ATOMIC_RELAXED, __HIP_MEMORY_SCOPE_AGENT);
        v0 += pa.f[0];
        v1 += pa.f[1];
      }
      v0 = fminf(fmaxf(v0, -3.f), 3.f);
      v1 = fminf(fmaxf(v1, -3.f), 3.f);
      bool active = t < len_f;
      u32 ho = __hip_atomic_load((u32*)(Hrep + ((size_t)(t & 1) * 8 + (jc & 7)) * Bz * Hz)
                                   + ((b_f * Hz + jf) >> 1),
                                 __ATOMIC_RELAXED, __HIP_MEMORY_SCOPE_AGENT);
      float hn0 = active ? v0 : bf2f((unsigned short)(ho & 0xffff));
      float hn1 = active ? v1 : bf2f((unsigned short)(ho >> 16));
      u32 hp = (u32)f2bf(hn0) | ((u32)f2bf(hn1) << 16);
      u32* hw32 = (u32*)(Hrep + (size_t)(((t & 1) ^ 1) * 8) * Bz * Hz);
      #pragma unroll
      for (int rep = 0; rep < 8; ++rep)
        __hip_atomic_store(hw32 + (size_t)rep * (Bz * Hz / 2) + ((b_f * Hz + jf) >> 1), hp,
                           __ATOMIC_RELAXED, __HIP_MEMORY_SCOPE_AGENT);
      __syncthreads();          // drain h replica stores
      if (tid == 0) {           // publish hflag replicas FIRST (unblocks grid)...
        __asm__ volatile("s_waitcnt vmcnt(0)" ::: "memory");
        #pragma unroll
        for (int rep = 0; rep < 8; ++rep)
          __hip_atomic_store(&hfl[(rep * 32 + jc) * 16], t + 1,
                             __ATOMIC_RELAXED, __HIP_MEMORY_SCOPE_AGENT);
      }
      // ...then output writes off the critical path
      floatx2 ov = {active ? v0 : 0.f, active ? v1 : 0.f};
      __builtin_nontemporal_store(ov, (floatx2*)(outp + ((size_t)b_f * Tz + t) * Hz + jf));
      if (t == Tz - 1) {
        __builtin_nontemporal_store(hn0, final_h + b_f * Hz + jf);
        __builtin_nontemporal_store(hn1, final_h + b_f * Hz + jf + 1);
      }
    }
  }
}

// ---------------- launcher ----------------

extern "C" void kernel_launch(void* const* d_in, const int* in_sizes, int n_in,
                              void* d_out, int out_size, void* d_ws, size_t ws_size,
                              hipStream_t stream) {
  const float* x   = (const float*)d_in[0];
  const int* lens  = (const int*)d_in[1];
  const float* Wi  = (const float*)d_in[2];
  const float* Wst = (const float*)d_in[3];
  const float* bst = (const float*)d_in[4];
  const float* Wp  = (const float*)d_in[5];

  float* outp    = (float*)d_out;
  float* final_h = outp + (size_t)Bz * Tz * Hz;
  float* final_c = final_h + (size_t)Bz * Hz;

  char* ws = (char*)d_ws;
  constexpr size_t OFF_HREP = 0;                                    // 1 MB (2x8 reps h bf16)
  constexpr size_t OFF_AFL  = OFF_HREP + 2 * 8 * (size_t)Bz * Hz * 2;   // 1,048,576
  constexpr size_t OFF_HFL  = OFF_AFL + 4 * 256 * 64;               // 1,114,112
  constexpr size_t OFF_PFL  = OFF_HFL + 8 * 32 * 64;                // 1,130,496
  constexpr size_t ZERO_END = OFF_PFL + 256 * 64;                   // 1,146,880
  constexpr size_t OFF_PART = ZERO_END;                             // 1 MB partials
  constexpr size_t OFF_AB   = OFF_PART + 8 * (size_t)Bz * Hz * 4;   // 4 MB abuf reps
  constexpr size_t OFF_WPK  = OFF_AB + 2 * 4 * (size_t)Bz * Cz * 2; // 32 MB
  constexpr size_t OFF_WPP  = OFF_WPK + (size_t)16384 * 1024 * 2;   // 4 MB
  constexpr size_t OFF_XB   = OFF_WPP + (size_t)Cz * Hz * 2;        // 32 MB
  constexpr size_t NEED     = OFF_XB + (size_t)Bz * Tz * Iz * 2;    // ~74.1 MB

  unsigned short* Hrep = (unsigned short*)(ws + OFF_HREP);
  int* afl      = (int*)(ws + OFF_AFL);
  int* hfl      = (int*)(ws + OFF_HFL);
  int* pfl      = (int*)(ws + OFF_PFL);
  float* part   = (float*)(ws + OFF_PART);
  unsigned short* abuf = (unsigned short*)(ws + OFF_AB);
  short* wpk    = (short*)(ws + OFF_WPK);
  short* wpp    = (short*)(ws + OFF_WPP);
  unsigned short* xb = (unsigned short*)(ws + OFF_XB);

  const bool packed = (ws_size >= NEED);

  hipMemsetAsync(ws, 0, ZERO_END, stream);   // h0 replicas + all flags

  if (packed) {
    precast_wpk<<<8192, 256, 0, stream>>>(Wi, Wst, wpk);
    precast_wpp<<<1024, 256, 0, stream>>>(Wp, wpp);
    precast_x<<<16384, 256, 0, stream>>>(x, xb);
  }

  if (packed) {
    lstm_persist<true><<<NWG, 512, 0, stream>>>(x, xb, Wi, Wst, Wp, wpk, wpp, bst, lens,
                                                Hrep, part, afl, hfl, pfl, abuf,
                                                outp, final_h, final_c);
  } else {
    lstm_persist<false><<<NWG, 512, 0, stream>>>(x, nullptr, Wi, Wst, Wp, nullptr, nullptr,
                                                 bst, lens, Hrep, part, afl, hfl, pfl, abuf,
                                                 outp, final_h, final_c);
  }
}